// Round 9
// baseline (90.437 us; speedup 1.0000x reference)
//
#include <hip/hip_runtime.h>

#define NCAP 10     // capsule classes c
#define NB   256    // batch b
#define NN   1152   // route nodes n
#define KI   8      // input dim i
#define NO   16     // output dim o
#define NT   1024   // threads per block (16 waves)
#define NWV  16
#define TB   2      // batches per block
#define NITER 3

__global__ __launch_bounds__(NT) void capsule_kernel(
    const float* __restrict__ x,    // [256,1152,8]
    const float* __restrict__ w,    // [10,1152,8,16]
    float* __restrict__ out)        // [10,256,16]
{
    // bf16-pair priors, [o_pair][tb][n ^ (op<<2)]:
    //  - XOR swizzle makes BOTH build writes (16 n-values x 4 ops/wave) and
    //    routing reads (n=t consecutive) 2 lanes/bank = free
    __shared__ unsigned s_pr[NO/2][TB][NN];   // 72 KB
    __shared__ float s_part[NWV][TB][NO];     // per-wave comp partials (4 KB)
    __shared__ float s_lsum[NWV][TB];         // per-wave exp-sum partials
    __shared__ float s_vw[NWV][TB][NO];       // per-wave private v copies (2 KB)

    const int t    = threadIdx.x;
    const int wv   = t >> 6;
    const int lane = t & 63;
    const int j    = t & 3;        // build: o-quad owned by this lane
    const int g    = t >> 2;       // build: cluster id, 0..255

    // XCD swizzle: 1280 % 8 == 0 -> bijective; same-c blocks share an XCD L2.
    const int bid = blockIdx.x;
    const int swz = (bid & 7) * (NCAP * (NB / TB) / 8) + (bid >> 3);
    const int c   = swz / (NB / TB);
    const int b0  = (swz % (NB / TB)) * TB;

    const int bl0 = lane & 1, bl1 = (lane >> 1) & 1,
              bl2 = (lane >> 2) & 1, bl3 = (lane >> 3) & 1;

    // iter-1 weighted sum (softmax(0) uniform) accumulated in f32 during build
    float bs[TB][4] = {{0.f,0.f,0.f,0.f},{0.f,0.f,0.f,0.f}};

    // ---- build: 4-lane cluster per n; lane j computes o-quad j ----
    // All 8 W quads preloaded into wq[8] BEFORE the FMA block: 8 loads in
    // flight -> one exposed L2 latency per round (round 8: 32 VGPRs forced
    // serialized 2-at-a-time loads).
    auto build_round = [&](int n) {
        float xs[TB][KI];
        #pragma unroll
        for (int tb = 0; tb < TB; ++tb) {
            const float4* xp = reinterpret_cast<const float4*>(
                x + ((size_t)(b0 + tb) * NN + n) * KI);
            float4 a = xp[0], b = xp[1];   // same addr across cluster -> bcast
            xs[tb][0]=a.x; xs[tb][1]=a.y; xs[tb][2]=a.z; xs[tb][3]=a.w;
            xs[tb][4]=b.x; xs[tb][5]=b.y; xs[tb][6]=b.z; xs[tb][7]=b.w;
        }
        const float4* wp = reinterpret_cast<const float4*>(
            w + ((size_t)c * NN + n) * (KI * NO));
        float4 wq[8];
        #pragma unroll
        for (int i = 0; i < KI; ++i) wq[i] = wp[i * 4 + j];  // dense 64B lines
        float acc[TB][4] = {{0.f,0.f,0.f,0.f},{0.f,0.f,0.f,0.f}};
        #pragma unroll
        for (int i = 0; i < KI; ++i) {
            #pragma unroll
            for (int tb = 0; tb < TB; ++tb) {
                acc[tb][0] = fmaf(xs[tb][i], wq[i].x, acc[tb][0]);
                acc[tb][1] = fmaf(xs[tb][i], wq[i].y, acc[tb][1]);
                acc[tb][2] = fmaf(xs[tb][i], wq[i].z, acc[tb][2]);
                acc[tb][3] = fmaf(xs[tb][i], wq[i].w, acc[tb][3]);
            }
        }
        const int o0 = 2 * j, o1 = 2 * j + 1;
        #pragma unroll
        for (int tb = 0; tb < TB; ++tb) {
            bs[tb][0] += acc[tb][0]; bs[tb][1] += acc[tb][1];
            bs[tb][2] += acc[tb][2]; bs[tb][3] += acc[tb][3];
            unsigned p0, p1;   // pair p: o=2p lo16, o=2p+1 hi16 (RNE)
            asm("v_cvt_pk_bf16_f32 %0, %1, %2"
                : "=v"(p0) : "v"(acc[tb][0]), "v"(acc[tb][1]));
            asm("v_cvt_pk_bf16_f32 %0, %1, %2"
                : "=v"(p1) : "v"(acc[tb][2]), "v"(acc[tb][3]));
            s_pr[o0][tb][n ^ (o0 << 2)] = p0;
            s_pr[o1][tb][n ^ (o1 << 2)] = p1;
        }
    };
    #pragma unroll 1
    for (int r = 0; r < 4; ++r) build_round(r * 256 + g);
    if (g < 128) build_round(1024 + g);      // wave-uniform (t < 512)

    // reduce bs across the wave's 16 clusters (same j): lanes 0..3 write
    #pragma unroll
    for (int tb = 0; tb < TB; ++tb)
        #pragma unroll
        for (int k = 0; k < 4; ++k) {
            float s = bs[tb][k];
            s += __shfl_xor(s, 4);  s += __shfl_xor(s, 8);
            s += __shfl_xor(s, 16); s += __shfl_xor(s, 32);
            bs[tb][k] = s;
        }
    if (lane < 4) {
        #pragma unroll
        for (int tb = 0; tb < TB; ++tb) {
            s_part[wv][tb][4*lane+0] = bs[tb][0];
            s_part[wv][tb][4*lane+1] = bs[tb][1];
            s_part[wv][tb][4*lane+2] = bs[tb][2];
            s_part[wv][tb][4*lane+3] = bs[tb][3];
        }
    }

    // ---- finalize: EVERY wave redundantly combines partials, squashes, and
    // writes its own s_vw slot (same-wave read-back needs no barrier) ----
    auto finalize = [&](int iter) {
        const int tb2 = (lane >> 4) & 1;    // 0-15:tb0 16-31:tb1 (dup 32-63)
        const int oc  = lane & 15;
        float acc = 0.f, lt = 0.f;
        #pragma unroll
        for (int w2 = 0; w2 < NWV; ++w2) {
            acc += s_part[w2][tb2][oc];     // same addr in 16-grp -> bcast
            if (iter > 0) lt += s_lsum[w2][tb2];
        }
        if (iter == 0) lt = (float)NN;      // softmax(0) is uniform
        float s_o = acc / lt;
        float sq = s_o * s_o;
        sq += __shfl_xor(sq, 1); sq += __shfl_xor(sq, 2);
        sq += __shfl_xor(sq, 4); sq += __shfl_xor(sq, 8);
        float scale = sq / ((1.f + sq) * sqrtf(sq));
        float vo = s_o * scale;
        if (lane < 32) s_vw[wv][tb2][oc] = vo;
        if (iter == NITER - 1 && wv == 0 && lane < 32)
            out[((size_t)c * NB + b0 + tb2) * NO + oc] = vo;
    };

    // consumption: thread owns n=t (and 1024+t if t<128) -> private logits;
    // delta + exp + weighted-sum fused in ONE pass over the bf16 priors.
    float logit[2][TB] = {{0.f,0.f},{0.f,0.f}};

    auto routing_pass = [&]() {
        #pragma unroll
        for (int tb = 0; tb < TB; ++tb) {
            float vv[NO];
            #pragma unroll
            for (int o = 0; o < NO; ++o) vv[o] = s_vw[wv][tb][o];  // bcast
            float sp[NO];
            #pragma unroll
            for (int o = 0; o < NO; ++o) sp[o] = 0.f;
            float lse = 0.f;
            #pragma unroll
            for (int rr = 0; rr < 2; ++rr) {
                if (rr == 1 && t >= 128) continue;   // wave-uniform
                const int n = rr * 1024 + t;
                float row[NO];
                #pragma unroll
                for (int op = 0; op < 8; ++op) {
                    unsigned u = s_pr[op][tb][n ^ (op << 2)];
                    row[2*op+0] = __uint_as_float(u << 16);
                    row[2*op+1] = __uint_as_float(u & 0xffff0000u);
                }
                float d0 = 0.f, d1 = 0.f;   // two 8-deep chains (vs one 16)
                #pragma unroll
                for (int o = 0; o < 8; ++o) {
                    d0 = fmaf(row[o],     vv[o],     d0);
                    d1 = fmaf(row[o + 8], vv[o + 8], d1);
                }
                logit[rr][tb] += d0 + d1;   // |logit| <~ 30: fp32 exact-safe
                float e = __expf(logit[rr][tb]);
                lse += e;
                #pragma unroll
                for (int o = 0; o < NO; ++o) sp[o] = fmaf(e, row[o], sp[o]);
            }
            // exp-sum: full-wave butterfly
            float s = lse;
            s += __shfl_xor(s, 1);  s += __shfl_xor(s, 2);
            s += __shfl_xor(s, 4);  s += __shfl_xor(s, 8);
            s += __shfl_xor(s, 16); s += __shfl_xor(s, 32);
            if (lane == 0) s_lsum[wv][tb] = s;
            // comp-halving fold: 16 comps over 16-lane groups in 15 shuffles
            float g8[8];
            #pragma unroll
            for (int r = 0; r < 8; ++r) {
                float keep = bl0 ? sp[2*r+1] : sp[2*r];
                float send = bl0 ? sp[2*r]   : sp[2*r+1];
                g8[r] = keep + __shfl_xor(send, 1);
            }
            float g4[4];
            #pragma unroll
            for (int r = 0; r < 4; ++r) {
                float keep = bl1 ? g8[2*r+1] : g8[2*r];
                float send = bl1 ? g8[2*r]   : g8[2*r+1];
                g4[r] = keep + __shfl_xor(send, 2);
            }
            float g2[2];
            #pragma unroll
            for (int r = 0; r < 2; ++r) {
                float keep = bl2 ? g4[2*r+1] : g4[2*r];
                float send = bl2 ? g4[2*r]   : g4[2*r+1];
                g2[r] = keep + __shfl_xor(send, 4);
            }
            float g1;
            {
                float keep = bl3 ? g2[1] : g2[0];
                float send = bl3 ? g2[0] : g2[1];
                g1 = keep + __shfl_xor(send, 8);
            }
            g1 += __shfl_xor(g1, 16);
            g1 += __shfl_xor(g1, 32);
            if (lane < NO) s_part[wv][tb][lane] = g1;
        }
    };

    __syncthreads();      // build + partials visible
    finalize(0);          // v1 (all waves, redundant)
    __syncthreads();      // protect s_part until all waves finished reading
    routing_pass();       // logits += prior.v1; partials for iter 2
    __syncthreads();
    finalize(1);          // v2
    __syncthreads();
    routing_pass();       // logits += prior.v2; partials for iter 3
    __syncthreads();
    finalize(2);          // v3 -> out (wave 0 writes)
}

extern "C" void kernel_launch(void* const* d_in, const int* in_sizes, int n_in,
                              void* d_out, int out_size, void* d_ws, size_t ws_size,
                              hipStream_t stream) {
    const float* x = (const float*)d_in[0];
    const float* w = (const float*)d_in[1];
    float* out = (float*)d_out;
    capsule_kernel<<<dim3(NCAP * (NB / TB)), dim3(NT), 0, stream>>>(x, w, out);
}

// Round 10
// 88.720 us; speedup vs baseline: 1.0194x; 1.0194x over previous
//
#include <hip/hip_runtime.h>

#define NCAP 10     // capsule classes c
#define NB   256    // batch b
#define NN   1152   // route nodes n
#define KI   8      // input dim i
#define NO   16     // output dim o
#define NT   1024   // threads per block (16 waves)
#define NWV  16
#define TB   2      // batches per block
#define NITER 3

__global__ __launch_bounds__(NT) void capsule_kernel(
    const float* __restrict__ x,    // [256,1152,8]
    const float* __restrict__ w,    // [10,1152,8,16]
    float* __restrict__ out)        // [10,256,16]
{
    // bf16-pair priors, [o_pair][tb][n ^ (op<<2)]: XOR swizzle makes BOTH
    // build writes and routing reads 2 lanes/bank = free (round 9: 0 confl).
    // LDS total kept at 76,032 B == round 8's footprint, which PROVED
    // 2-block/CU co-residency (73% occ); round 9's +2 KB broke it (43%).
    __shared__ unsigned s_pr[NO/2][TB][NN];   // 72 KB
    __shared__ float s_part[NWV][TB][NO];     // per-wave comp partials (2 KB)
    __shared__ float s_lsum[NWV][TB];         // per-wave exp-sum partials
    __shared__ float s_v[TB][NO];             // squashed v broadcast (128 B)

    const int t    = threadIdx.x;
    const int wv   = t >> 6;
    const int lane = t & 63;
    const int j    = t & 3;        // build: o-quad owned by this lane
    const int g    = t >> 2;       // build: cluster id, 0..255

    // XCD swizzle: 1280 % 8 == 0 -> bijective; same-c blocks share an XCD L2.
    const int bid = blockIdx.x;
    const int swz = (bid & 7) * (NCAP * (NB / TB) / 8) + (bid >> 3);
    const int c   = swz / (NB / TB);
    const int b0  = (swz % (NB / TB)) * TB;

    const int bl0 = lane & 1, bl1 = (lane >> 1) & 1,
              bl2 = (lane >> 2) & 1, bl3 = (lane >> 3) & 1;

    // iter-1 weighted sum (softmax(0) uniform) accumulated in f32 during build
    float bs[TB][4] = {{0.f,0.f,0.f,0.f},{0.f,0.f,0.f,0.f}};

    // ---- build: 4-lane cluster per n; lane j computes o-quad j ----
    // All 8 W quads preloaded BEFORE the FMA block: 8 loads in flight -> one
    // exposed L2 latency per round.
    auto build_round = [&](int n) {
        float xs[TB][KI];
        #pragma unroll
        for (int tb = 0; tb < TB; ++tb) {
            const float4* xp = reinterpret_cast<const float4*>(
                x + ((size_t)(b0 + tb) * NN + n) * KI);
            float4 a = xp[0], b = xp[1];   // same addr across cluster -> bcast
            xs[tb][0]=a.x; xs[tb][1]=a.y; xs[tb][2]=a.z; xs[tb][3]=a.w;
            xs[tb][4]=b.x; xs[tb][5]=b.y; xs[tb][6]=b.z; xs[tb][7]=b.w;
        }
        const float4* wp = reinterpret_cast<const float4*>(
            w + ((size_t)c * NN + n) * (KI * NO));
        float4 wq[8];
        #pragma unroll
        for (int i = 0; i < KI; ++i) wq[i] = wp[i * 4 + j];  // dense 64B lines
        float acc[TB][4] = {{0.f,0.f,0.f,0.f},{0.f,0.f,0.f,0.f}};
        #pragma unroll
        for (int i = 0; i < KI; ++i) {
            #pragma unroll
            for (int tb = 0; tb < TB; ++tb) {
                acc[tb][0] = fmaf(xs[tb][i], wq[i].x, acc[tb][0]);
                acc[tb][1] = fmaf(xs[tb][i], wq[i].y, acc[tb][1]);
                acc[tb][2] = fmaf(xs[tb][i], wq[i].z, acc[tb][2]);
                acc[tb][3] = fmaf(xs[tb][i], wq[i].w, acc[tb][3]);
            }
        }
        const int o0 = 2 * j, o1 = 2 * j + 1;
        #pragma unroll
        for (int tb = 0; tb < TB; ++tb) {
            bs[tb][0] += acc[tb][0]; bs[tb][1] += acc[tb][1];
            bs[tb][2] += acc[tb][2]; bs[tb][3] += acc[tb][3];
            unsigned p0, p1;   // pair p: o=2p lo16, o=2p+1 hi16 (RNE)
            asm("v_cvt_pk_bf16_f32 %0, %1, %2"
                : "=v"(p0) : "v"(acc[tb][0]), "v"(acc[tb][1]));
            asm("v_cvt_pk_bf16_f32 %0, %1, %2"
                : "=v"(p1) : "v"(acc[tb][2]), "v"(acc[tb][3]));
            s_pr[o0][tb][n ^ (o0 << 2)] = p0;
            s_pr[o1][tb][n ^ (o1 << 2)] = p1;
        }
    };
    #pragma unroll 1
    for (int r = 0; r < 4; ++r) build_round(r * 256 + g);
    if (g < 128) build_round(1024 + g);      // wave-uniform (t < 512)

    // reduce bs across the wave's 16 clusters (same j): lanes 0..3 write
    #pragma unroll
    for (int tb = 0; tb < TB; ++tb)
        #pragma unroll
        for (int k = 0; k < 4; ++k) {
            float s = bs[tb][k];
            s += __shfl_xor(s, 4);  s += __shfl_xor(s, 8);
            s += __shfl_xor(s, 16); s += __shfl_xor(s, 32);
            bs[tb][k] = s;
        }
    if (lane < 4) {
        #pragma unroll
        for (int tb = 0; tb < TB; ++tb) {
            s_part[wv][tb][4*lane+0] = bs[tb][0];
            s_part[wv][tb][4*lane+1] = bs[tb][1];
            s_part[wv][tb][4*lane+2] = bs[tb][2];
            s_part[wv][tb][4*lane+3] = bs[tb][3];
        }
    }

    // ---- finalize: EVERY wave redundantly combines partials + squashes (no
    // single-wave serialization); wave 0 publishes to the 128-B s_v ----
    auto finalize = [&](int iter) {
        const int tb2 = (lane >> 4) & 1;    // 0-15:tb0 16-31:tb1 (dup 32-63)
        const int oc  = lane & 15;
        float acc = 0.f, lt = 0.f;
        #pragma unroll
        for (int w2 = 0; w2 < NWV; ++w2) {
            acc += s_part[w2][tb2][oc];     // same addr in 16-grp -> bcast
            if (iter > 0) lt += s_lsum[w2][tb2];
        }
        if (iter == 0) lt = (float)NN;      // softmax(0) is uniform
        float s_o = acc / lt;
        float sq = s_o * s_o;
        sq += __shfl_xor(sq, 1); sq += __shfl_xor(sq, 2);
        sq += __shfl_xor(sq, 4); sq += __shfl_xor(sq, 8);
        float scale = sq / ((1.f + sq) * sqrtf(sq));
        float vo = s_o * scale;
        if (wv == 0 && lane < 32) {
            s_v[tb2][oc] = vo;
            if (iter == NITER - 1)
                out[((size_t)c * NB + b0 + tb2) * NO + oc] = vo;
        }
    };

    // consumption: thread owns n=t (and 1024+t if t<128) -> private logits;
    // delta + exp + weighted-sum fused in ONE pass over the bf16 priors.
    float logit[2][TB] = {{0.f,0.f},{0.f,0.f}};

    auto routing_pass = [&]() {
        #pragma unroll
        for (int tb = 0; tb < TB; ++tb) {
            float vv[NO];
            #pragma unroll
            for (int o = 0; o < NO; ++o) vv[o] = s_v[tb][o];   // LDS bcast
            float sp[NO];
            #pragma unroll
            for (int o = 0; o < NO; ++o) sp[o] = 0.f;
            float lse = 0.f;
            #pragma unroll
            for (int rr = 0; rr < 2; ++rr) {
                if (rr == 1 && t >= 128) continue;   // wave-uniform
                const int n = rr * 1024 + t;
                float row[NO];
                #pragma unroll
                for (int op = 0; op < 8; ++op) {
                    unsigned u = s_pr[op][tb][n ^ (op << 2)];
                    row[2*op+0] = __uint_as_float(u << 16);
                    row[2*op+1] = __uint_as_float(u & 0xffff0000u);
                }
                float d0 = 0.f, d1 = 0.f;   // two 8-deep chains
                #pragma unroll
                for (int o = 0; o < 8; ++o) {
                    d0 = fmaf(row[o],     vv[o],     d0);
                    d1 = fmaf(row[o + 8], vv[o + 8], d1);
                }
                logit[rr][tb] += d0 + d1;   // |logit| <~ 30: fp32 exact-safe
                float e = __expf(logit[rr][tb]);
                lse += e;
                #pragma unroll
                for (int o = 0; o < NO; ++o) sp[o] = fmaf(e, row[o], sp[o]);
            }
            // exp-sum: full-wave butterfly
            float s = lse;
            s += __shfl_xor(s, 1);  s += __shfl_xor(s, 2);
            s += __shfl_xor(s, 4);  s += __shfl_xor(s, 8);
            s += __shfl_xor(s, 16); s += __shfl_xor(s, 32);
            if (lane == 0) s_lsum[wv][tb] = s;
            // comp-halving fold: 16 comps over 16-lane groups in 15 shuffles
            float g8[8];
            #pragma unroll
            for (int r = 0; r < 8; ++r) {
                float keep = bl0 ? sp[2*r+1] : sp[2*r];
                float send = bl0 ? sp[2*r]   : sp[2*r+1];
                g8[r] = keep + __shfl_xor(send, 1);
            }
            float g4[4];
            #pragma unroll
            for (int r = 0; r < 4; ++r) {
                float keep = bl1 ? g8[2*r+1] : g8[2*r];
                float send = bl1 ? g8[2*r]   : g8[2*r+1];
                g4[r] = keep + __shfl_xor(send, 2);
            }
            float g2[2];
            #pragma unroll
            for (int r = 0; r < 2; ++r) {
                float keep = bl2 ? g4[2*r+1] : g4[2*r];
                float send = bl2 ? g4[2*r]   : g4[2*r+1];
                g2[r] = keep + __shfl_xor(send, 4);
            }
            float g1;
            {
                float keep = bl3 ? g2[1] : g2[0];
                float send = bl3 ? g2[0] : g2[1];
                g1 = keep + __shfl_xor(send, 8);
            }
            g1 += __shfl_xor(g1, 16);
            g1 += __shfl_xor(g1, 32);
            if (lane < NO) s_part[wv][tb][lane] = g1;
        }
    };

    __syncthreads();      // build + partials visible
    finalize(0);          // v1 (all waves redundant; wave 0 writes s_v)
    __syncthreads();      // s_v visible; s_part safe to overwrite
    routing_pass();       // logits += prior.v1; partials for iter 2
    __syncthreads();
    finalize(1);          // v2
    __syncthreads();
    routing_pass();       // logits += prior.v2; partials for iter 3
    __syncthreads();
    finalize(2);          // v3 -> out (wave 0 writes)
}

extern "C" void kernel_launch(void* const* d_in, const int* in_sizes, int n_in,
                              void* d_out, int out_size, void* d_ws, size_t ws_size,
                              hipStream_t stream) {
    const float* x = (const float*)d_in[0];
    const float* w = (const float*)d_in[1];
    float* out = (float*)d_out;
    capsule_kernel<<<dim3(NCAP * (NB / TB)), dim3(NT), 0, stream>>>(x, w, out);
}